// Round 3
// baseline (538.483 us; speedup 1.0000x reference)
//
#include <hip/hip_runtime.h>

#define DIM 64
#define EPS 1e-8f
#define ALPHA_T 0.1f

// ---------------- norm: one wave per node, lane-per-dim ----------------
__global__ void norm_kernel(const float* __restrict__ embs,
                            float* __restrict__ inv_norm, int n_nodes) {
    int node = (blockIdx.x * blockDim.x + threadIdx.x) >> 6;
    int lane = threadIdx.x & 63;
    if (node >= n_nodes) return;
    float v = embs[node * DIM + lane];
    float ss = v * v;
    #pragma unroll
    for (int m = 1; m < 64; m <<= 1) ss += __shfl_xor(ss, m);
    if (lane == 0) inv_norm[node] = 1.0f / fmaxf(sqrtf(ss), EPS);
}

// ---------------- CSR build ----------------
__global__ void count_kernel(const int* __restrict__ rows, int* __restrict__ cnt, int E) {
    int e = blockIdx.x * blockDim.x + threadIdx.x;
    if (e < E) atomicAdd(&cnt[rows[e]], 1);
}

// grid.x = 2 (one block per edge set); exclusive scan cnt[0..n) -> rp[0..n]
__global__ void scan_kernel(const int* __restrict__ cnt0, int* __restrict__ rp0,
                            const int* __restrict__ cnt1, int* __restrict__ rp1, int n) {
    const int* cnt = blockIdx.x ? cnt1 : cnt0;
    int* rp = blockIdx.x ? rp1 : rp0;
    __shared__ int wsum[16];
    __shared__ int s_carry;
    int tid = threadIdx.x, lane = tid & 63, wid = tid >> 6;
    if (tid == 0) s_carry = 0;
    __syncthreads();
    for (int base = 0; base < n; base += 1024) {
        int i = base + tid;
        int x = (i < n) ? cnt[i] : 0;
        int inc = x;
        #pragma unroll
        for (int off = 1; off < 64; off <<= 1) {
            int y = __shfl_up(inc, off);
            if (lane >= off) inc += y;
        }
        if (lane == 63) wsum[wid] = inc;
        __syncthreads();                       // wsum ready
        int carry = s_carry;
        int woff = 0;
        for (int w = 0; w < wid; ++w) woff += wsum[w];
        if (i < n) rp[i] = carry + woff + inc - x;
        int tot = 0;
        if (tid == 0) { for (int w = 0; w < 16; ++w) tot += wsum[w]; }
        __syncthreads();                       // everyone read s_carry/wsum
        if (tid == 0) s_carry = carry + tot;
        __syncthreads();                       // update visible, wsum reusable
    }
    if (threadIdx.x == 0) rp[n] = s_carry;
}

__global__ void fill_kernel(const int* __restrict__ eidx, const float* __restrict__ ev,
                            const int* __restrict__ rp, int* __restrict__ cur,
                            int* __restrict__ scol, float* __restrict__ sval, int E) {
    int e = blockIdx.x * blockDim.x + threadIdx.x;
    if (e >= E) return;
    int r = eidx[e];
    int c = eidx[E + e];
    int slot = rp[r] + atomicAdd(&cur[r], 1);
    scol[slot] = c;
    sval[slot] = ev[e];
}

// ---------------- fused refine + SpMM, one wave per row, no atomics ----------------
template <bool SECOND>
__global__ void spmm_csr_kernel(const float* __restrict__ embs,
                                const float* __restrict__ xg,       // gathered array (msg_tar) when SECOND
                                const float* __restrict__ inv_norm,
                                const int* __restrict__ rp,
                                const int* __restrict__ scol,
                                const float* __restrict__ sval,
                                float* __restrict__ out, int n_rows) {
    int r = (blockIdx.x * blockDim.x + threadIdx.x) >> 6;
    int lane = threadIdx.x & 63;
    if (r >= n_rows) return;

    float q = embs[r * DIM + lane];
    float inv_r = inv_norm[r];
    int beg = rp[r], end = rp[r + 1];
    float acc = 0.0f;

    for (int s = beg; s < end; ++s) {
        int c = scol[s];
        float w = sval[s];
        float v = embs[c * DIM + lane];
        float xv = SECOND ? xg[c * DIM + lane] : v;
        float inv_c = inv_norm[c];
        float dot = q * v;
        #pragma unroll
        for (int m = 1; m < 64; m <<= 1) dot += __shfl_xor(dot, m);
        float sim = dot * inv_r * inv_c;
        float sn = fminf(fmaxf((sim + 1.0f) * 0.5f, 0.0f), 1.0f);
        float refined = w * (1.0f + ALPHA_T * sn);
        acc += refined * xv;
    }
    out[r * DIM + lane] = acc;
}

// ---------------- round-1 fallback (atomic scatter) if ws too small ----------------
__global__ void refine_spmm_atomic(const float* __restrict__ embs,
                                   const float* __restrict__ x,
                                   const int* __restrict__ eidx,
                                   const float* __restrict__ eval_,
                                   const float* __restrict__ inv_norm,
                                   float* __restrict__ out, int n_edges) {
    int wave = (blockIdx.x * blockDim.x + threadIdx.x) >> 6;
    int lane = threadIdx.x & 63;
    if (wave >= n_edges) return;
    int r0 = eidx[wave];
    int r1 = eidx[n_edges + wave];
    float s = embs[r0 * DIM + lane];
    float t = embs[r1 * DIM + lane];
    float dot = s * t;
    #pragma unroll
    for (int m = 1; m < 64; m <<= 1) dot += __shfl_xor(dot, m);
    float sim = dot * inv_norm[r0] * inv_norm[r1];
    float sn = fminf(fmaxf((sim + 1.0f) * 0.5f, 0.0f), 1.0f);
    float refined = eval_[wave] * (1.0f + ALPHA_T * sn);
    float xv = (x == embs) ? t : x[r1 * DIM + lane];
    atomicAdd(&out[r0 * DIM + lane], refined * xv);
}

extern "C" void kernel_launch(void* const* d_in, const int* in_sizes, int n_in,
                              void* d_out, int out_size, void* d_ws, size_t ws_size,
                              hipStream_t stream) {
    const float* embs    = (const float*)d_in[0];
    const int*   src_idx = (const int*)d_in[1];
    const float* src_val = (const float*)d_in[2];
    const int*   tar_idx = (const int*)d_in[3];
    const float* tar_val = (const float*)d_in[4];
    float* out = (float*)d_out;

    int n = in_sizes[0] / DIM;       // 50000
    int E = in_sizes[2];             // 800000
    size_t ND = (size_t)n * DIM;

    // workspace layout
    int*   cnts   = (int*)d_ws;            // 4n: cnt_t, cur_t, cnt_s, cur_s
    int*   cnt_t  = cnts;
    int*   cur_t  = cnts + n;
    int*   cnt_s  = cnts + 2 * n;
    int*   cur_s  = cnts + 3 * n;
    int*   rp_t   = cnts + 4 * n;          // n+1
    int*   rp_s   = rp_t + (n + 1);        // n+1
    int*   scol_t = rp_s + (n + 1);        // E
    float* sval_t = (float*)(scol_t + E);  // E
    int*   scol_s = (int*)(sval_t + E);    // E
    float* sval_s = (float*)(scol_s + E);  // E
    float* invn   = sval_s + E;            // n
    float* msg    = invn + n;              // ND
    size_t needed = ((size_t)4 * n + 2 * (n + 1) + 4 * (size_t)E + n + ND) * 4;

    int nodeBlocks = (n * 64 + 255) / 256;   // wave-per-node/row grids
    int edgeBlocks = (E + 255) / 256;

    if (ws_size >= needed) {
        hipMemsetAsync(cnts, 0, (size_t)4 * n * sizeof(int), stream);
        norm_kernel<<<nodeBlocks, 256, 0, stream>>>(embs, invn, n);
        count_kernel<<<edgeBlocks, 256, 0, stream>>>(tar_idx, cnt_t, E);
        count_kernel<<<edgeBlocks, 256, 0, stream>>>(src_idx, cnt_s, E);
        scan_kernel<<<2, 1024, 0, stream>>>(cnt_t, rp_t, cnt_s, rp_s, n);
        fill_kernel<<<edgeBlocks, 256, 0, stream>>>(tar_idx, tar_val, rp_t, cur_t, scol_t, sval_t, E);
        fill_kernel<<<edgeBlocks, 256, 0, stream>>>(src_idx, src_val, rp_s, cur_s, scol_s, sval_s, E);
        // SpMM 1: msg = A_tar(refined) @ embs
        spmm_csr_kernel<false><<<nodeBlocks, 256, 0, stream>>>(embs, nullptr, invn, rp_t, scol_t, sval_t, msg, n);
        // SpMM 2: out = A_src(refined) @ msg
        spmm_csr_kernel<true><<<nodeBlocks, 256, 0, stream>>>(embs, msg, invn, rp_s, scol_s, sval_s, out, n);
    } else {
        // fallback: round-1 atomic path (needs (n + ND)*4 bytes)
        float* inv_norm = (float*)d_ws;
        float* msg_tar  = inv_norm + n;
        hipMemsetAsync(msg_tar, 0, ND * sizeof(float), stream);
        hipMemsetAsync(d_out, 0, (size_t)out_size * sizeof(float), stream);
        norm_kernel<<<nodeBlocks, 256, 0, stream>>>(embs, inv_norm, n);
        refine_spmm_atomic<<<(E * 64 + 255) / 256, 256, 0, stream>>>(
            embs, embs, tar_idx, tar_val, inv_norm, msg_tar, E);
        refine_spmm_atomic<<<(E * 64 + 255) / 256, 256, 0, stream>>>(
            embs, msg_tar, src_idx, src_val, inv_norm, out, E);
    }
}

// Round 4
// 474.117 us; speedup vs baseline: 1.1358x; 1.1358x over previous
//
#include <hip/hip_runtime.h>

#define DIM 64
#define EPS 1e-8f
#define ALPHA_T 0.1f

// ---- norm + normalized-f16 table: one wave per node ----
__global__ void norm_hat_kernel(const float* __restrict__ embs,
                                _Float16* __restrict__ hat,
                                float* __restrict__ nrm, int n) {
    int node = (blockIdx.x * blockDim.x + threadIdx.x) >> 6;
    int lane = threadIdx.x & 63;
    if (node >= n) return;
    float v = embs[node * DIM + lane];
    float ss = v * v;
    #pragma unroll
    for (int m = 1; m < 64; m <<= 1) ss += __shfl_xor(ss, m);
    float nr = fmaxf(sqrtf(ss), EPS);
    hat[node * DIM + lane] = (_Float16)(v / nr);
    if (lane == 0) nrm[node] = nr;
}

// ---- count rows of both edge sets (grid.y selects set) ----
__global__ void count_kernel(const int* __restrict__ t_idx, const int* __restrict__ s_idx,
                             int* __restrict__ cnt_t, int* __restrict__ cnt_s, int E) {
    int e = blockIdx.x * blockDim.x + threadIdx.x;
    if (e >= E) return;
    if (blockIdx.y == 0) atomicAdd(&cnt_t[t_idx[e]], 1);
    else                 atomicAdd(&cnt_s[s_idx[e]], 1);
}

// ---- scan level 1: per-block (512 elems) exclusive scan IN PLACE + block sums ----
__global__ void scan1_kernel(int* __restrict__ rp_t, int* __restrict__ rp_s,
                             int* __restrict__ bs_t, int* __restrict__ bs_s, int n) {
    int* rp = blockIdx.y ? rp_s : rp_t;
    int* bs = blockIdx.y ? bs_s : bs_t;
    __shared__ int wsum[8];
    int tid = threadIdx.x, lane = tid & 63, wid = tid >> 6;
    int i = blockIdx.x * 512 + tid;
    int x = (i < n) ? rp[i] : 0;        // read BEFORE barrier (in-place safe)
    int inc = x;
    #pragma unroll
    for (int off = 1; off < 64; off <<= 1) {
        int y = __shfl_up(inc, off);
        if (lane >= off) inc += y;
    }
    if (lane == 63) wsum[wid] = inc;
    __syncthreads();
    int woff = 0;
    #pragma unroll
    for (int w = 0; w < 8; ++w) if (w < wid) woff += wsum[w];
    if (i < n) rp[i] = woff + inc - x;  // write AFTER barrier
    if (tid == 0) {
        int tot = 0;
        #pragma unroll
        for (int w = 0; w < 8; ++w) tot += wsum[w];
        bs[blockIdx.x] = tot;
    }
}

// ---- scan level 2: exclusive scan of block sums, one wave per set ----
__global__ void scan2_kernel(int* __restrict__ bs_t, int* __restrict__ bs_s, int nb) {
    int* bs = blockIdx.x ? bs_s : bs_t;
    int lane = threadIdx.x;
    int carry = 0;
    for (int base = 0; base < nb; base += 64) {
        int i = base + lane;
        int x = (i < nb) ? bs[i] : 0;
        int inc = x;
        #pragma unroll
        for (int off = 1; off < 64; off <<= 1) {
            int y = __shfl_up(inc, off);
            if (lane >= off) inc += y;
        }
        if (i < nb) bs[i] = carry + inc - x;
        carry += __shfl(inc, 63);
    }
}

// ---- fill: scatter (col,val) pairs into CSR slots; cur[r] ends as row count ----
__global__ void fill_kernel(const int* __restrict__ t_idx, const float* __restrict__ t_val,
                            const int* __restrict__ s_idx, const float* __restrict__ s_val,
                            const int* __restrict__ rp_t, const int* __restrict__ rp_s,
                            const int* __restrict__ bo_t, const int* __restrict__ bo_s,
                            int* __restrict__ cur_t, int* __restrict__ cur_s,
                            int2* __restrict__ pr_t, int2* __restrict__ pr_s, int E) {
    int e = blockIdx.x * blockDim.x + threadIdx.x;
    if (e >= E) return;
    const int* idx; const float* val; const int* rp; const int* bo; int* cur; int2* pr;
    if (blockIdx.y == 0) { idx = t_idx; val = t_val; rp = rp_t; bo = bo_t; cur = cur_t; pr = pr_t; }
    else                 { idx = s_idx; val = s_val; rp = rp_s; bo = bo_s; cur = cur_s; pr = pr_s; }
    int r = idx[e];
    int c = idx[E + e];
    float v = val[e];
    int slot = rp[r] + bo[r >> 9] + atomicAdd(&cur[r], 1);
    pr[slot] = make_int2(c, __float_as_int(v));
}

// ---- fused refine + SpMM, one wave per row, f16 gathers, no atomics ----
template <bool SECOND>
__global__ void spmm_kernel(const _Float16* __restrict__ hat,
                            const _Float16* __restrict__ msg_h,
                            const float* __restrict__ nrm,
                            const int* __restrict__ rp,
                            const int* __restrict__ bo,
                            const int* __restrict__ cur,
                            const int2* __restrict__ pairs,
                            float* __restrict__ out_f32,
                            _Float16* __restrict__ out_f16,
                            int n_rows) {
    int r = (blockIdx.x * blockDim.x + threadIdx.x) >> 6;
    int lane = threadIdx.x & 63;
    if (r >= n_rows) return;
    float q = (float)hat[r * DIM + lane];
    int beg = rp[r] + bo[r >> 9];
    int cnt = cur[r];
    float acc = 0.0f;
    int2 p;
    if (cnt > 0) p = pairs[beg];
    for (int k = 0; k < cnt; ++k) {
        int2 pn;
        if (k + 1 < cnt) pn = pairs[beg + k + 1];   // prefetch next pair
        int c = p.x;
        float w = __int_as_float(p.y);
        float cv = (float)hat[c * DIM + lane];
        float mv = 0.0f;
        if (SECOND) mv = (float)msg_h[c * DIM + lane];
        float dot = q * cv;
        #pragma unroll
        for (int m = 1; m < 64; m <<= 1) dot += __shfl_xor(dot, m);
        float sn = fminf(fmaxf((dot + 1.0f) * 0.5f, 0.0f), 1.0f);
        float wr = w * (1.0f + ALPHA_T * sn);
        if (SECOND) acc += wr * mv;
        else        acc += (wr * nrm[c]) * cv;
        p = pn;
    }
    if (SECOND) out_f32[r * DIM + lane] = acc;
    else        out_f16[r * DIM + lane] = (_Float16)acc;
}

// ---- fallback: atomic scatter path (round-1) ----
__global__ void norm_kernel_f(const float* __restrict__ embs,
                              float* __restrict__ inv_norm, int n_nodes) {
    int node = (blockIdx.x * blockDim.x + threadIdx.x) >> 6;
    int lane = threadIdx.x & 63;
    if (node >= n_nodes) return;
    float v = embs[node * DIM + lane];
    float ss = v * v;
    #pragma unroll
    for (int m = 1; m < 64; m <<= 1) ss += __shfl_xor(ss, m);
    if (lane == 0) inv_norm[node] = 1.0f / fmaxf(sqrtf(ss), EPS);
}

__global__ void refine_spmm_atomic(const float* __restrict__ embs,
                                   const float* __restrict__ x,
                                   const int* __restrict__ eidx,
                                   const float* __restrict__ eval_,
                                   const float* __restrict__ inv_norm,
                                   float* __restrict__ out, int n_edges) {
    int wave = (blockIdx.x * blockDim.x + threadIdx.x) >> 6;
    int lane = threadIdx.x & 63;
    if (wave >= n_edges) return;
    int r0 = eidx[wave];
    int r1 = eidx[n_edges + wave];
    float s = embs[r0 * DIM + lane];
    float t = embs[r1 * DIM + lane];
    float dot = s * t;
    #pragma unroll
    for (int m = 1; m < 64; m <<= 1) dot += __shfl_xor(dot, m);
    float sim = dot * inv_norm[r0] * inv_norm[r1];
    float sn = fminf(fmaxf((sim + 1.0f) * 0.5f, 0.0f), 1.0f);
    float refined = eval_[wave] * (1.0f + ALPHA_T * sn);
    float xv = (x == embs) ? t : x[r1 * DIM + lane];
    atomicAdd(&out[r0 * DIM + lane], refined * xv);
}

extern "C" void kernel_launch(void* const* d_in, const int* in_sizes, int n_in,
                              void* d_out, int out_size, void* d_ws, size_t ws_size,
                              hipStream_t stream) {
    const float* embs    = (const float*)d_in[0];
    const int*   src_idx = (const int*)d_in[1];
    const float* src_val = (const float*)d_in[2];
    const int*   tar_idx = (const int*)d_in[3];
    const float* tar_val = (const float*)d_in[4];
    float* out = (float*)d_out;

    int n = in_sizes[0] / DIM;       // 50000
    int E = in_sizes[2];             // 800000
    int nb = (n + 511) / 512;        // scan blocks per set

    // workspace layout (4-byte words)
    int* w      = (int*)d_ws;
    int* rp_t   = w;                       // n   (count -> in-place local-excl scan)
    int* rp_s   = rp_t + n;                // n
    int* cur_t  = rp_s + n;                // n   (fill slot counters -> row counts)
    int* cur_s  = cur_t + n;               // n
    int* bo_t   = cur_s + n;               // nb  (block sums -> block offsets)
    int* bo_s   = bo_t + nb;               // nb
    float* nrm  = (float*)(bo_s + nb);     // n
    size_t po   = (size_t)(6 * n) + 2 * nb;
    po = (po + 1) & ~(size_t)1;            // int2 alignment
    int2* pr_t  = (int2*)(w + po);         // E pairs (2E words)
    int2* pr_s  = pr_t + E;                // E pairs
    _Float16* hat   = (_Float16*)(pr_s + E);   // n*DIM halves (32n words)
    _Float16* msg_h = hat + (size_t)n * DIM;   // n*DIM halves
    size_t needed = (po + 4 * (size_t)E + 64 * (size_t)n) * 4;

    int nodeBlocks = (n * 64 + 255) / 256;
    int eb = (E + 255) / 256;

    if (ws_size >= needed) {
        hipMemsetAsync(w, 0, (size_t)4 * n * sizeof(int), stream);  // rp_* + cur_*
        norm_hat_kernel<<<nodeBlocks, 256, 0, stream>>>(embs, hat, nrm, n);
        count_kernel<<<dim3(eb, 2), 256, 0, stream>>>(tar_idx, src_idx, rp_t, rp_s, E);
        scan1_kernel<<<dim3(nb, 2), 512, 0, stream>>>(rp_t, rp_s, bo_t, bo_s, n);
        scan2_kernel<<<2, 64, 0, stream>>>(bo_t, bo_s, nb);
        fill_kernel<<<dim3(eb, 2), 256, 0, stream>>>(tar_idx, tar_val, src_idx, src_val,
                                                     rp_t, rp_s, bo_t, bo_s,
                                                     cur_t, cur_s, pr_t, pr_s, E);
        // SpMM 1: msg_h = A_tar(refined) @ embs   (f16 out)
        spmm_kernel<false><<<nodeBlocks, 256, 0, stream>>>(
            hat, nullptr, nrm, rp_t, bo_t, cur_t, pr_t, nullptr, msg_h, n);
        // SpMM 2: out = A_src(refined) @ msg      (f32 out)
        spmm_kernel<true><<<nodeBlocks, 256, 0, stream>>>(
            hat, msg_h, nrm, rp_s, bo_s, cur_s, pr_s, out, nullptr, n);
    } else {
        // fallback: atomic path (needs (n + n*DIM)*4 bytes)
        float* inv_norm = (float*)d_ws;
        float* msg_tar  = inv_norm + n;
        hipMemsetAsync(msg_tar, 0, (size_t)n * DIM * sizeof(float), stream);
        hipMemsetAsync(d_out, 0, (size_t)out_size * sizeof(float), stream);
        norm_kernel_f<<<nodeBlocks, 256, 0, stream>>>(embs, inv_norm, n);
        refine_spmm_atomic<<<(E * 64 + 255) / 256, 256, 0, stream>>>(
            embs, embs, tar_idx, tar_val, inv_norm, msg_tar, E);
        refine_spmm_atomic<<<(E * 64 + 255) / 256, 256, 0, stream>>>(
            embs, msg_tar, src_idx, src_val, inv_norm, out, E);
    }
}

// Round 6
// 322.054 us; speedup vs baseline: 1.6720x; 1.4722x over previous
//
#include <hip/hip_runtime.h>

#define DIM 64
#define EPS 1e-8f
#define ALPHA_T 0.1f

typedef _Float16 f16x8 __attribute__((ext_vector_type(8)));

// ---- norm + normalized-f16 table: one wave per node ----
__global__ void norm_hat_kernel(const float* __restrict__ embs,
                                _Float16* __restrict__ hat,
                                float* __restrict__ nrm, int n) {
    int node = (blockIdx.x * blockDim.x + threadIdx.x) >> 6;
    int lane = threadIdx.x & 63;
    if (node >= n) return;
    float v = embs[node * DIM + lane];
    float ss = v * v;
    #pragma unroll
    for (int m = 1; m < 64; m <<= 1) ss += __shfl_xor(ss, m);
    float nr = fmaxf(sqrtf(ss), EPS);
    hat[node * DIM + lane] = (_Float16)(v / nr);
    if (lane == 0) nrm[node] = nr;
}

// ---- count rows of both edge sets (grid.y selects set) ----
__global__ void count_kernel(const int* __restrict__ t_idx, const int* __restrict__ s_idx,
                             int* __restrict__ cnt_t, int* __restrict__ cnt_s, int E) {
    int e = blockIdx.x * blockDim.x + threadIdx.x;
    if (e >= E) return;
    if (blockIdx.y == 0) atomicAdd(&cnt_t[t_idx[e]], 1);
    else                 atomicAdd(&cnt_s[s_idx[e]], 1);
}

// ---- scan level 1: per-block (512 elems) exclusive scan IN PLACE + block sums ----
__global__ void scan1_kernel(int* __restrict__ rp_t, int* __restrict__ rp_s,
                             int* __restrict__ bs_t, int* __restrict__ bs_s, int n) {
    int* rp = blockIdx.y ? rp_s : rp_t;
    int* bs = blockIdx.y ? bs_s : bs_t;
    __shared__ int wsum[8];
    int tid = threadIdx.x, lane = tid & 63, wid = tid >> 6;
    int i = blockIdx.x * 512 + tid;
    int x = (i < n) ? rp[i] : 0;        // read BEFORE barrier (in-place safe)
    int inc = x;
    #pragma unroll
    for (int off = 1; off < 64; off <<= 1) {
        int y = __shfl_up(inc, off);
        if (lane >= off) inc += y;
    }
    if (lane == 63) wsum[wid] = inc;
    __syncthreads();
    int woff = 0;
    #pragma unroll
    for (int w = 0; w < 8; ++w) if (w < wid) woff += wsum[w];
    if (i < n) rp[i] = woff + inc - x;  // write AFTER barrier
    if (tid == 0) {
        int tot = 0;
        #pragma unroll
        for (int w = 0; w < 8; ++w) tot += wsum[w];
        bs[blockIdx.x] = tot;
    }
}

// ---- scan level 2: exclusive scan of block sums, one wave per set ----
__global__ void scan2_kernel(int* __restrict__ bs_t, int* __restrict__ bs_s, int nb) {
    int* bs = blockIdx.x ? bs_s : bs_t;
    int lane = threadIdx.x;
    int carry = 0;
    for (int base = 0; base < nb; base += 64) {
        int i = base + lane;
        int x = (i < nb) ? bs[i] : 0;
        int inc = x;
        #pragma unroll
        for (int off = 1; off < 64; off <<= 1) {
            int y = __shfl_up(inc, off);
            if (lane >= off) inc += y;
        }
        if (i < nb) bs[i] = carry + inc - x;
        carry += __shfl(inc, 63);
    }
}

// ---- fill: scatter (col,val) pairs into CSR slots; cur[r] ends as row count ----
__global__ void fill_kernel(const int* __restrict__ t_idx, const float* __restrict__ t_val,
                            const int* __restrict__ s_idx, const float* __restrict__ s_val,
                            const int* __restrict__ rp_t, const int* __restrict__ rp_s,
                            const int* __restrict__ bo_t, const int* __restrict__ bo_s,
                            int* __restrict__ cur_t, int* __restrict__ cur_s,
                            int2* __restrict__ pr_t, int2* __restrict__ pr_s, int E) {
    int e = blockIdx.x * blockDim.x + threadIdx.x;
    if (e >= E) return;
    const int* idx; const float* val; const int* rp; const int* bo; int* cur; int2* pr;
    if (blockIdx.y == 0) { idx = t_idx; val = t_val; rp = rp_t; bo = bo_t; cur = cur_t; pr = pr_t; }
    else                 { idx = s_idx; val = s_val; rp = rp_s; bo = bo_s; cur = cur_s; pr = pr_s; }
    int r = idx[e];
    int c = idx[E + e];
    float v = val[e];
    int slot = rp[r] + bo[r >> 9] + atomicAdd(&cur[r], 1);
    pr[slot] = make_int2(c, __float_as_int(v));
}

// ---- fused refine + SpMM: one wave per row, 8 edges in flight (8 lanes/edge) ----
// group g = lane>>3 owns edge slot g; lane handles dims [(lane&7)*8 .. +7] as f16x8.
template <bool SECOND>
__global__ void spmm_kernel(const _Float16* __restrict__ hat,
                            const _Float16* __restrict__ msg_h,
                            const float* __restrict__ nrm,
                            const int* __restrict__ rp,
                            const int* __restrict__ bo,
                            const int* __restrict__ cur,
                            const int2* __restrict__ pairs,
                            float* __restrict__ out_f32,
                            _Float16* __restrict__ out_f16,
                            int n_rows) {
    int r = (blockIdx.x * blockDim.x + threadIdx.x) >> 6;
    int lane = threadIdx.x & 63;
    if (r >= n_rows) return;
    int g = lane >> 3;          // edge slot within wave
    int l = lane & 7;           // dim-octet index

    f16x8 qh = *(const f16x8*)&hat[(size_t)r * DIM + l * 8];
    float qf[8];
    #pragma unroll
    for (int i = 0; i < 8; ++i) qf[i] = (float)qh[i];

    int beg = rp[r] + bo[r >> 9];
    int cnt = cur[r];
    float acc[8] = {0, 0, 0, 0, 0, 0, 0, 0};

    int2 p = (g < cnt) ? pairs[beg + g] : make_int2(0, 0);
    for (int k0 = 0; k0 < cnt; k0 += 8) {
        int nidx = k0 + 8 + g;
        int2 pn = (nidx < cnt) ? pairs[beg + nidx] : make_int2(0, 0);

        int c = p.x;
        float w = __int_as_float(p.y);        // 0.0f for invalid lanes
        f16x8 ch = *(const f16x8*)&hat[(size_t)c * DIM + l * 8];

        float dot = 0.0f;
        #pragma unroll
        for (int i = 0; i < 8; ++i) dot += qf[i] * (float)ch[i];
        #pragma unroll
        for (int m = 1; m < 8; m <<= 1) dot += __shfl_xor(dot, m);   // within group

        float sn = fminf(fmaxf((dot + 1.0f) * 0.5f, 0.0f), 1.0f);
        float wr = w * (1.0f + ALPHA_T * sn);

        if (SECOND) {
            f16x8 mh = *(const f16x8*)&msg_h[(size_t)c * DIM + l * 8];
            #pragma unroll
            for (int i = 0; i < 8; ++i) acc[i] += wr * (float)mh[i];
        } else {
            float s = wr * nrm[c];
            #pragma unroll
            for (int i = 0; i < 8; ++i) acc[i] += s * (float)ch[i];
        }
        p = pn;
    }

    // cross-group reduce (masks 8,16,32)
    #pragma unroll
    for (int m = 8; m < 64; m <<= 1) {
        #pragma unroll
        for (int i = 0; i < 8; ++i) acc[i] += __shfl_xor(acc[i], m);
    }

    if (g == 0) {
        if (SECOND) {
            float4* o = (float4*)&out_f32[(size_t)r * DIM + l * 8];
            o[0] = make_float4(acc[0], acc[1], acc[2], acc[3]);
            o[1] = make_float4(acc[4], acc[5], acc[6], acc[7]);
        } else {
            f16x8 h;
            #pragma unroll
            for (int i = 0; i < 8; ++i) h[i] = (_Float16)acc[i];
            *(f16x8*)&out_f16[(size_t)r * DIM + l * 8] = h;
        }
    }
}

// ---- fallback: atomic scatter path ----
__global__ void norm_kernel_f(const float* __restrict__ embs,
                              float* __restrict__ inv_norm, int n_nodes) {
    int node = (blockIdx.x * blockDim.x + threadIdx.x) >> 6;
    int lane = threadIdx.x & 63;
    if (node >= n_nodes) return;
    float v = embs[node * DIM + lane];
    float ss = v * v;
    #pragma unroll
    for (int m = 1; m < 64; m <<= 1) ss += __shfl_xor(ss, m);
    if (lane == 0) inv_norm[node] = 1.0f / fmaxf(sqrtf(ss), EPS);
}

__global__ void refine_spmm_atomic(const float* __restrict__ embs,
                                   const float* __restrict__ x,
                                   const int* __restrict__ eidx,
                                   const float* __restrict__ eval_,
                                   const float* __restrict__ inv_norm,
                                   float* __restrict__ out, int n_edges) {
    int wave = (blockIdx.x * blockDim.x + threadIdx.x) >> 6;
    int lane = threadIdx.x & 63;
    if (wave >= n_edges) return;
    int r0 = eidx[wave];
    int r1 = eidx[n_edges + wave];
    float s = embs[r0 * DIM + lane];
    float t = embs[r1 * DIM + lane];
    float dot = s * t;
    #pragma unroll
    for (int m = 1; m < 64; m <<= 1) dot += __shfl_xor(dot, m);
    float sim = dot * inv_norm[r0] * inv_norm[r1];
    float sn = fminf(fmaxf((sim + 1.0f) * 0.5f, 0.0f), 1.0f);
    float refined = eval_[wave] * (1.0f + ALPHA_T * sn);
    float xv = (x == embs) ? t : x[r1 * DIM + lane];
    atomicAdd(&out[r0 * DIM + lane], refined * xv);
}

extern "C" void kernel_launch(void* const* d_in, const int* in_sizes, int n_in,
                              void* d_out, int out_size, void* d_ws, size_t ws_size,
                              hipStream_t stream) {
    const float* embs    = (const float*)d_in[0];
    const int*   src_idx = (const int*)d_in[1];
    const float* src_val = (const float*)d_in[2];
    const int*   tar_idx = (const int*)d_in[3];
    const float* tar_val = (const float*)d_in[4];
    float* out = (float*)d_out;

    int n = in_sizes[0] / DIM;       // 50000
    int E = in_sizes[2];             // 800000
    int nb = (n + 511) / 512;        // scan blocks per set

    // workspace layout (4-byte words)
    int* w      = (int*)d_ws;
    int* rp_t   = w;                       // n   (count -> in-place local-excl scan)
    int* rp_s   = rp_t + n;                // n
    int* cur_t  = rp_s + n;                // n   (fill slot counters -> row counts)
    int* cur_s  = cur_t + n;               // n
    int* bo_t   = cur_s + n;               // nb  (block sums -> block offsets)
    int* bo_s   = bo_t + nb;               // nb
    float* nrm  = (float*)(bo_s + nb);     // n
    size_t po   = (size_t)(6 * n) + 2 * nb;
    po = (po + 3) & ~(size_t)3;            // 16B alignment for pairs/hat
    int2* pr_t  = (int2*)(w + po);         // E pairs (2E words)
    int2* pr_s  = pr_t + E;                // E pairs
    _Float16* hat   = (_Float16*)(pr_s + E);   // n*DIM halves (32n words)
    _Float16* msg_h = hat + (size_t)n * DIM;   // n*DIM halves
    size_t needed = (po + 4 * (size_t)E + 64 * (size_t)n) * 4;

    int nodeBlocks = (n * 64 + 255) / 256;
    int eb = (E + 255) / 256;

    if (ws_size >= needed) {
        hipMemsetAsync(w, 0, (size_t)4 * n * sizeof(int), stream);  // rp_* + cur_*
        norm_hat_kernel<<<nodeBlocks, 256, 0, stream>>>(embs, hat, nrm, n);
        count_kernel<<<dim3(eb, 2), 256, 0, stream>>>(tar_idx, src_idx, rp_t, rp_s, E);
        scan1_kernel<<<dim3(nb, 2), 512, 0, stream>>>(rp_t, rp_s, bo_t, bo_s, n);
        scan2_kernel<<<2, 64, 0, stream>>>(bo_t, bo_s, nb);
        fill_kernel<<<dim3(eb, 2), 256, 0, stream>>>(tar_idx, tar_val, src_idx, src_val,
                                                     rp_t, rp_s, bo_t, bo_s,
                                                     cur_t, cur_s, pr_t, pr_s, E);
        // SpMM 1: msg_h = A_tar(refined) @ embs   (f16 out)
        spmm_kernel<false><<<nodeBlocks, 256, 0, stream>>>(
            hat, nullptr, nrm, rp_t, bo_t, cur_t, pr_t, nullptr, msg_h, n);
        // SpMM 2: out = A_src(refined) @ msg      (f32 out)
        spmm_kernel<true><<<nodeBlocks, 256, 0, stream>>>(
            hat, msg_h, nrm, rp_s, bo_s, cur_s, pr_s, out, nullptr, n);
    } else {
        // fallback: atomic path (needs (n + n*DIM)*4 bytes)
        float* inv_norm = (float*)d_ws;
        float* msg_tar  = inv_norm + n;
        hipMemsetAsync(msg_tar, 0, (size_t)n * DIM * sizeof(float), stream);
        hipMemsetAsync(d_out, 0, (size_t)out_size * sizeof(float), stream);
        norm_kernel_f<<<nodeBlocks, 256, 0, stream>>>(embs, inv_norm, n);
        refine_spmm_atomic<<<(E * 64 + 255) / 256, 256, 0, stream>>>(
            embs, embs, tar_idx, tar_val, inv_norm, msg_tar, E);
        refine_spmm_atomic<<<(E * 64 + 255) / 256, 256, 0, stream>>>(
            embs, msg_tar, src_idx, src_val, inv_norm, out, E);
    }
}

// Round 8
// 211.009 us; speedup vs baseline: 2.5519x; 1.5263x over previous
//
#include <hip/hip_runtime.h>

#define DIM 64
#define EPS 1e-8f
#define ALPHA_T 0.1f
#define BSH 8                 // bucket = 256 rows
#define FINE_CAP 14336        // LDS staging capacity (57 KB); mean bucket = 4096

typedef _Float16 f16x8 __attribute__((ext_vector_type(8)));

static __device__ __forceinline__ unsigned short f32_to_f16bits(float f) {
    union { _Float16 h; unsigned short u; } cv; cv.h = (_Float16)f; return cv.u;
}
static __device__ __forceinline__ float f16bits_to_f32(unsigned short u) {
    union { _Float16 h; unsigned short u; } cv; cv.u = u; return (float)cv.h;
}

// ---- norm + normalized-f16 table: one wave per node ----
__global__ void norm_hat_kernel(const float* __restrict__ embs,
                                _Float16* __restrict__ hat,
                                float* __restrict__ nrm, int n) {
    int node = (blockIdx.x * blockDim.x + threadIdx.x) >> 6;
    int lane = threadIdx.x & 63;
    if (node >= n) return;
    float v = embs[node * DIM + lane];
    float ss = v * v;
    #pragma unroll
    for (int m = 1; m < 64; m <<= 1) ss += __shfl_xor(ss, m);
    float nr = fmaxf(sqrtf(ss), EPS);
    hat[node * DIM + lane] = (_Float16)(v / nr);
    if (lane == 0) nrm[node] = nr;
}

// ---- per-bucket histogram (LDS-merged) ----
__global__ void bucket_hist_kernel(const int* __restrict__ t_idx, const int* __restrict__ s_idx,
                                   int* __restrict__ bhist, int E, int nbk) {
    __shared__ int h[256];
    const int* idx = blockIdx.y ? s_idx : t_idx;
    int tid = threadIdx.x;
    h[tid] = 0;
    __syncthreads();
    for (int e = blockIdx.x * blockDim.x + tid; e < E; e += gridDim.x * blockDim.x)
        atomicAdd(&h[idx[e] >> BSH], 1);
    __syncthreads();
    if (tid < nbk && h[tid]) atomicAdd(&bhist[blockIdx.y * nbk + tid], h[tid]);
}

// ---- exclusive scan of bucket counts -> bucket bases (1 wave per set) ----
__global__ void bucket_scan_kernel(const int* __restrict__ bhist, int* __restrict__ bo, int nbk) {
    const int* h = bhist + blockIdx.x * nbk;
    int* o = bo + blockIdx.x * nbk;
    int lane = threadIdx.x;
    int carry = 0;
    for (int base = 0; base < nbk; base += 64) {
        int i = base + lane;
        int x = (i < nbk) ? h[i] : 0;
        int inc = x;
        #pragma unroll
        for (int off = 1; off < 64; off <<= 1) {
            int y = __shfl_up(inc, off);
            if (lane >= off) inc += y;
        }
        if (i < nbk) o[i] = carry + inc - x;
        carry += __shfl(inc, 63);
    }
}

// ---- multisplit: bin tile of 4096 edges by bucket in LDS, write coalesced runs ----
__global__ void fill_ms_kernel(const int* __restrict__ t_idx, const float* __restrict__ t_val,
                               const int* __restrict__ s_idx, const float* __restrict__ s_val,
                               const int* __restrict__ bo, int* __restrict__ bcur,
                               int2* __restrict__ coarse, int E, int nbk) {
    __shared__ int hist[256];
    __shared__ int excl[256];
    __shared__ int cur[256];
    __shared__ int gbase[256];
    __shared__ int2 stage[4096];
    int set = blockIdx.y;
    const int* idx = set ? s_idx : t_idx;
    const float* val = set ? s_val : t_val;
    int tid = threadIdx.x;
    int tile0 = blockIdx.x * 4096;
    hist[tid] = 0; cur[tid] = 0;
    __syncthreads();
    int r_[16]; int m_[16]; float v_[16];
    #pragma unroll
    for (int i = 0; i < 16; ++i) {
        int j = tile0 + i * 256 + tid;
        if (j < E) {
            int r = idx[j];
            int c = idx[E + j];
            r_[i] = r;
            m_[i] = (c & 0xFFFF) | ((r & 255) << 16);  // c:16b | r_local:8b
            v_[i] = val[j];
            atomicAdd(&hist[r >> BSH], 1);
        } else r_[i] = -1;
    }
    __syncthreads();
    // exclusive scan hist -> excl (Hillis-Steele over 256)
    int x = hist[tid];
    excl[tid] = x;
    __syncthreads();
    for (int off = 1; off < 256; off <<= 1) {
        int y = (tid >= off) ? excl[tid - off] : 0;
        __syncthreads();
        excl[tid] += y;
        __syncthreads();
    }
    int myexc = excl[tid] - x;
    __syncthreads();
    excl[tid] = myexc;
    if (tid < nbk && x > 0)
        gbase[tid] = bo[set * nbk + tid] + atomicAdd(&bcur[set * nbk + tid], x);
    __syncthreads();
    // stage bucket-grouped
    #pragma unroll
    for (int i = 0; i < 16; ++i) {
        if (r_[i] >= 0) {
            int b = r_[i] >> BSH;
            int p = excl[b] + atomicAdd(&cur[b], 1);
            stage[p] = make_int2(m_[i], __float_as_int(v_[i]));
        }
    }
    __syncthreads();
    // copy out per-bucket runs (wave-parallel, coalesced)
    int wv = tid >> 6, ln = tid & 63;
    int2* cset = coarse + (size_t)set * E;
    for (int b = wv; b < nbk; b += 4) {
        int cb = hist[b];
        if (!cb) continue;
        int sb = excl[b];
        int gb = gbase[b];
        for (int k = ln; k < cb; k += 64)
            cset[gb + k] = stage[sb + k];
    }
}

// ---- fine pass: per-bucket row grouping in LDS; emits rp_abs/cnt + packed pairs ----
__global__ void fill_fine_kernel(const int2* __restrict__ coarse,
                                 const int* __restrict__ bo, const int* __restrict__ bhist,
                                 unsigned int* __restrict__ pairs,
                                 int* __restrict__ rp_abs, int* __restrict__ cnt,
                                 int E, int n, int nbk) {
    __shared__ int h[256];
    __shared__ int exc[256];
    __shared__ int cur[256];
    __shared__ unsigned int outbuf[FINE_CAP];
    int set = blockIdx.y;
    int b = blockIdx.x;
    const int2* src = coarse + (size_t)set * E;
    unsigned int* dst = pairs + (size_t)set * E;
    int base = bo[set * nbk + b];
    int cb   = bhist[set * nbk + b];
    int tid = threadIdx.x;
    h[tid] = 0; cur[tid] = 0;
    __syncthreads();
    for (int k = tid; k < cb; k += 256)
        atomicAdd(&h[(src[base + k].x >> 16) & 255], 1);
    __syncthreads();
    int x = h[tid];
    exc[tid] = x;
    __syncthreads();
    for (int off = 1; off < 256; off <<= 1) {
        int y = (tid >= off) ? exc[tid - off] : 0;
        __syncthreads();
        exc[tid] += y;
        __syncthreads();
    }
    int myexc = exc[tid] - x;
    __syncthreads();
    exc[tid] = myexc;
    int r = (b << BSH) + tid;
    if (r < n) {
        rp_abs[set * n + r] = base + myexc;
        cnt[set * n + r] = x;
    }
    __syncthreads();
    bool ovf = cb > FINE_CAP;
    for (int k = tid; k < cb; k += 256) {
        int2 pr = src[base + k];
        int rl = (pr.x >> 16) & 255;
        unsigned int packed = (unsigned int)(pr.x & 0xFFFF)
                            | ((unsigned int)f32_to_f16bits(__int_as_float(pr.y)) << 16);
        int slot = exc[rl] + atomicAdd(&cur[rl], 1);
        if (!ovf) outbuf[slot] = packed;
        else      dst[base + slot] = packed;   // impossible-by-stats fallback
    }
    __syncthreads();
    if (!ovf)
        for (int k = tid; k < cb; k += 256)
            dst[base + k] = outbuf[k];
}

// ---- fused refine + SpMM: one wave per row, 8 edges in flight, packed 4B pairs ----
template <bool SECOND>
__global__ void spmm_kernel(const _Float16* __restrict__ hat,
                            const _Float16* __restrict__ msg_h,
                            const float* __restrict__ nrm,
                            const int* __restrict__ rp_abs,
                            const int* __restrict__ cnt,
                            const unsigned int* __restrict__ pairs,
                            float* __restrict__ out_f32,
                            _Float16* __restrict__ out_f16,
                            int n_rows) {
    int r = (blockIdx.x * blockDim.x + threadIdx.x) >> 6;
    int lane = threadIdx.x & 63;
    if (r >= n_rows) return;
    int g = lane >> 3;          // edge slot within wave
    int l = lane & 7;           // dim-octet index

    f16x8 qh = *(const f16x8*)&hat[(size_t)r * DIM + l * 8];
    float qf[8];
    #pragma unroll
    for (int i = 0; i < 8; ++i) qf[i] = (float)qh[i];

    int beg = rp_abs[r];
    int c_ = cnt[r];
    float acc[8] = {0, 0, 0, 0, 0, 0, 0, 0};

    unsigned int p = (g < c_) ? pairs[beg + g] : 0u;
    for (int k0 = 0; k0 < c_; k0 += 8) {
        int nidx = k0 + 8 + g;
        unsigned int pn = (nidx < c_) ? pairs[beg + nidx] : 0u;

        int c = p & 0xFFFF;
        float w = f16bits_to_f32((unsigned short)(p >> 16));   // 0 for invalid lanes
        f16x8 ch = *(const f16x8*)&hat[(size_t)c * DIM + l * 8];

        float dot = 0.0f;
        #pragma unroll
        for (int i = 0; i < 8; ++i) dot += qf[i] * (float)ch[i];
        #pragma unroll
        for (int m = 1; m < 8; m <<= 1) dot += __shfl_xor(dot, m);

        float sn = fminf(fmaxf((dot + 1.0f) * 0.5f, 0.0f), 1.0f);
        float wr = w * (1.0f + ALPHA_T * sn);

        if (SECOND) {
            f16x8 mh = *(const f16x8*)&msg_h[(size_t)c * DIM + l * 8];
            #pragma unroll
            for (int i = 0; i < 8; ++i) acc[i] += wr * (float)mh[i];
        } else {
            float s = wr * nrm[c];
            #pragma unroll
            for (int i = 0; i < 8; ++i) acc[i] += s * (float)ch[i];
        }
        p = pn;
    }

    #pragma unroll
    for (int m = 8; m < 64; m <<= 1) {
        #pragma unroll
        for (int i = 0; i < 8; ++i) acc[i] += __shfl_xor(acc[i], m);
    }

    if (g == 0) {
        if (SECOND) {
            float4* o = (float4*)&out_f32[(size_t)r * DIM + l * 8];
            o[0] = make_float4(acc[0], acc[1], acc[2], acc[3]);
            o[1] = make_float4(acc[4], acc[5], acc[6], acc[7]);
        } else {
            f16x8 hv;
            #pragma unroll
            for (int i = 0; i < 8; ++i) hv[i] = (_Float16)acc[i];
            *(f16x8*)&out_f16[(size_t)r * DIM + l * 8] = hv;
        }
    }
}

// ---- fallback: atomic scatter path ----
__global__ void norm_kernel_f(const float* __restrict__ embs,
                              float* __restrict__ inv_norm, int n_nodes) {
    int node = (blockIdx.x * blockDim.x + threadIdx.x) >> 6;
    int lane = threadIdx.x & 63;
    if (node >= n_nodes) return;
    float v = embs[node * DIM + lane];
    float ss = v * v;
    #pragma unroll
    for (int m = 1; m < 64; m <<= 1) ss += __shfl_xor(ss, m);
    if (lane == 0) inv_norm[node] = 1.0f / fmaxf(sqrtf(ss), EPS);
}

__global__ void refine_spmm_atomic(const float* __restrict__ embs,
                                   const float* __restrict__ x,
                                   const int* __restrict__ eidx,
                                   const float* __restrict__ eval_,
                                   const float* __restrict__ inv_norm,
                                   float* __restrict__ out, int n_edges) {
    int wave = (blockIdx.x * blockDim.x + threadIdx.x) >> 6;
    int lane = threadIdx.x & 63;
    if (wave >= n_edges) return;
    int r0 = eidx[wave];
    int r1 = eidx[n_edges + wave];
    float s = embs[r0 * DIM + lane];
    float t = embs[r1 * DIM + lane];
    float dot = s * t;
    #pragma unroll
    for (int m = 1; m < 64; m <<= 1) dot += __shfl_xor(dot, m);
    float sim = dot * inv_norm[r0] * inv_norm[r1];
    float sn = fminf(fmaxf((sim + 1.0f) * 0.5f, 0.0f), 1.0f);
    float refined = eval_[wave] * (1.0f + ALPHA_T * sn);
    float xv = (x == embs) ? t : x[r1 * DIM + lane];
    atomicAdd(&out[r0 * DIM + lane], refined * xv);
}

extern "C" void kernel_launch(void* const* d_in, const int* in_sizes, int n_in,
                              void* d_out, int out_size, void* d_ws, size_t ws_size,
                              hipStream_t stream) {
    const float* embs    = (const float*)d_in[0];
    const int*   src_idx = (const int*)d_in[1];
    const float* src_val = (const float*)d_in[2];
    const int*   tar_idx = (const int*)d_in[3];
    const float* tar_val = (const float*)d_in[4];
    float* out = (float*)d_out;

    int n = in_sizes[0] / DIM;       // 50000
    int E = in_sizes[2];             // 800000
    int nbk = (n + 255) >> BSH;      // 196 buckets per set

    // workspace layout (words)
    int* w = (int*)d_ws;
    size_t wo = 0;
    int* bhist = w + wo; wo += 2 * (size_t)nbk;
    int* bcur  = w + wo; wo += 2 * (size_t)nbk;
    int* bo    = w + wo; wo += 2 * (size_t)nbk;
    int* rp    = w + wo; wo += 2 * (size_t)n;   // per set: rp_abs
    int* cnt   = w + wo; wo += 2 * (size_t)n;   // per set: row counts
    float* nrm = (float*)(w + wo); wo += (size_t)n;
    wo = (wo + 3) & ~(size_t)3;
    unsigned int* pairs = (unsigned int*)(w + wo); wo += 2 * (size_t)E;
    wo = (wo + 3) & ~(size_t)3;
    // region: coarse pairs (dead after fill_fine) aliases hat+msg
    size_t region_words = (size_t)4 * E > (size_t)64 * n ? (size_t)4 * E : (size_t)64 * n;
    int2* coarse    = (int2*)(w + wo);
    _Float16* hat   = (_Float16*)(w + wo);
    _Float16* msg_h = hat + (size_t)n * DIM;
    wo += region_words;
    size_t needed = wo * 4;

    int nodeBlocks = (n * 64 + 255) / 256;
    int tiles = (E + 4095) / 4096;

    if (ws_size >= needed && n <= 65536 && nbk <= 256) {
        hipMemsetAsync(bhist, 0, 4 * (size_t)nbk * sizeof(int), stream);  // bhist + bcur
        bucket_hist_kernel<<<dim3(256, 2), 256, 0, stream>>>(tar_idx, src_idx, bhist, E, nbk);
        bucket_scan_kernel<<<2, 64, 0, stream>>>(bhist, bo, nbk);
        fill_ms_kernel<<<dim3(tiles, 2), 256, 0, stream>>>(
            tar_idx, tar_val, src_idx, src_val, bo, bcur, coarse, E, nbk);
        fill_fine_kernel<<<dim3(nbk, 2), 256, 0, stream>>>(
            coarse, bo, bhist, pairs, rp, cnt, E, n, nbk);
        // coarse dead; hat/msg alias it from here on
        norm_hat_kernel<<<nodeBlocks, 256, 0, stream>>>(embs, hat, nrm, n);
        // SpMM 1 (tar, set 0): msg = A_tar(refined) @ embs  (f16 out)
        spmm_kernel<false><<<nodeBlocks, 256, 0, stream>>>(
            hat, nullptr, nrm, rp, cnt, pairs, nullptr, msg_h, n);
        // SpMM 2 (src, set 1): out = A_src(refined) @ msg   (f32 out)
        spmm_kernel<true><<<nodeBlocks, 256, 0, stream>>>(
            hat, msg_h, nrm, rp + n, cnt + n, pairs + (size_t)E, out, nullptr, n);
    } else {
        // fallback: atomic path (needs (n + n*DIM)*4 bytes)
        float* inv_norm = (float*)d_ws;
        float* msg_tar  = inv_norm + n;
        hipMemsetAsync(msg_tar, 0, (size_t)n * DIM * sizeof(float), stream);
        hipMemsetAsync(d_out, 0, (size_t)out_size * sizeof(float), stream);
        norm_kernel_f<<<nodeBlocks, 256, 0, stream>>>(embs, inv_norm, n);
        refine_spmm_atomic<<<(E * 64 + 255) / 256, 256, 0, stream>>>(
            embs, embs, tar_idx, tar_val, inv_norm, msg_tar, E);
        refine_spmm_atomic<<<(E * 64 + 255) / 256, 256, 0, stream>>>(
            embs, msg_tar, src_idx, src_val, inv_norm, out, E);
    }
}